// Round 1
// baseline (798.823 us; speedup 1.0000x reference)
//
#include <hip/hip_runtime.h>
#include <hip/hip_bf16.h>

#define D_FEAT 128
#define D4 (D_FEAT / 4)
#define BKT_SHIFT 7            // 128 nodes per bucket
#define BKT_NODES 128
#define MAXBKT 512
#define K1_HIST_BLOCKS 256
#define K1_CVT_BLOCKS 256
#define K3_BLOCKS 256

// pack two floats as bf16 pair (lo in low 16 bits)
__device__ inline unsigned pack_bf2(float lo, float hi) {
    __hip_bfloat162 h = __float22bfloat162_rn(make_float2(lo, hi));
    unsigned u;
    __builtin_memcpy(&u, &h, 4);
    return u;
}

// ---- K1: per-block LDS histogram -> global per-bucket counts (atomic);
//      blocks >= K1_HIST_BLOCKS convert features to PAIRED bf16 layout:
//      fb[n*64 + k] = pack(f[n][k], f[n][k+64])   (k in 0..63)
__global__ __launch_bounds__(256) void k1_hist_cvt(
        const int* __restrict__ dst, int E, int nbkt,
        int* __restrict__ counts,
        const float4* __restrict__ fin4, uint4* __restrict__ fout4, int N) {
    int c = blockIdx.x;
    int tid = threadIdx.x;
    if (c < K1_HIST_BLOCKS) {
        __shared__ int hist[MAXBKT];
        for (int i = tid; i < nbkt; i += 256) hist[i] = 0;
        __syncthreads();
        int chunk = (E + K1_HIST_BLOCKS - 1) / K1_HIST_BLOCKS;
        int lo = c * chunk;
        int hi = min(lo + chunk, E);
        for (int i = lo + tid; i < hi; i += 256)
            atomicAdd(&hist[dst[i] >> BKT_SHIFT], 1);
        __syncthreads();
        for (int i = tid; i < nbkt; i += 256) {
            int h = hist[i];
            if (h) atomicAdd(&counts[i], h);
        }
    } else {
        int idx = (c - K1_HIST_BLOCKS) * 256 + tid;
        int stride = (gridDim.x - K1_HIST_BLOCKS) * 256;
        int total = N * 16;                    // one uint4 (4 packed pairs) each
        for (int i = idx; i < total; i += stride) {
            int n = i >> 4;
            int k4 = i & 15;
            float4 a = fin4[n * 32 + k4];      // feats 4k4..4k4+3
            float4 b = fin4[n * 32 + 16 + k4]; // feats 64+4k4..
            uint4 o;
            o.x = pack_bf2(a.x, b.x);
            o.y = pack_bf2(a.y, b.y);
            o.z = pack_bf2(a.z, b.z);
            o.w = pack_bf2(a.w, b.w);
            fout4[n * 16 + k4] = o;
        }
    }
}

// ---- K3: partition edges into per-bucket contiguous ranges.
//      Each block: LDS scan of global counts (bases) -> chunk histogram ->
//      reserve a contiguous sub-range per bucket via one global atomic ->
//      scatter through LDS cursors (runs of ~8 edges -> 64B write locality).
//      Block 0 also publishes the scanned bases for K45.
__global__ __launch_bounds__(512) void k3_partition(
        const int* __restrict__ src, const int* __restrict__ dst,
        const float* __restrict__ vals, int E, int nbkt,
        const int* __restrict__ counts, int* __restrict__ gcur,
        int* __restrict__ gbase, int2* __restrict__ spackA) {
    __shared__ int s[MAXBKT];
    __shared__ int lh[MAXBKT];
    __shared__ int lcur[MAXBKT];
    int c = blockIdx.x;
    int tid = threadIdx.x;
    // Hillis-Steele inclusive scan over MAXBKT (=512) with 512 threads
    int v = (tid < nbkt) ? counts[tid] : 0;
    s[tid] = v;
    __syncthreads();
    for (int off = 1; off < MAXBKT; off <<= 1) {
        int t = (tid >= off) ? s[tid - off] : 0;
        __syncthreads();
        s[tid] += t;
        __syncthreads();
    }
    int excl = s[tid] - v;
    s[tid] = excl;                 // own slot only; no cross-read until next barrier
    if (c == 0 && tid < nbkt) gbase[tid] = excl;
    lh[tid] = 0;
    __syncthreads();
    int chunk = (E + K3_BLOCKS - 1) / K3_BLOCKS;
    int lo = c * chunk;
    int hi = min(lo + chunk, E);
    for (int i = lo + tid; i < hi; i += 512)
        atomicAdd(&lh[dst[i] >> BKT_SHIFT], 1);
    __syncthreads();
    if (tid < nbkt) {
        int h = lh[tid];
        lcur[tid] = h ? (s[tid] + atomicAdd(&gcur[tid], h)) : 0;
    }
    __syncthreads();
    for (int i = lo + tid; i < hi; i += 512) {
        int d = dst[i];
        int pos = atomicAdd(&lcur[d >> BKT_SHIFT], 1);
        spackA[pos] = make_int2((src[i] & 0xFFFF) | ((d & (BKT_NODES - 1)) << 16),
                                __float_as_int(vals[i]));
    }
}

// ---- K45: per-bucket accumulation into a 128x128 fp32 LDS tile via
//      ds_add_f32 (paired layout -> both atomics are 2-way bank-free),
//      flat 8-edge-unrolled wave loop (no sort, no per-node remainders),
//      then coalesced bias+writeout.
__global__ __launch_bounds__(1024) void k45_accum(
        const int* __restrict__ counts, const int* __restrict__ gbase,
        const int2* __restrict__ spackA, const unsigned* __restrict__ fbu,
        const float4* __restrict__ bias4, float4* __restrict__ out4, int N) {
    __shared__ float acc[BKT_NODES * D_FEAT];   // 64 KiB
    int b = blockIdx.x;
    int tid = threadIdx.x;
    float4* acc4 = (float4*)acc;
    float4 z = make_float4(0.f, 0.f, 0.f, 0.f);
    for (int i = tid; i < BKT_NODES * D_FEAT / 4; i += 1024) acc4[i] = z;
    __syncthreads();

    int base = gbase[b];
    int cnt = counts[b];
    int wid = tid >> 6, lane = tid & 63;
    const int2* ep = spackA + base;
    int nfull = cnt >> 3;
    for (int g0 = wid; g0 < nfull; g0 += 16) {
        int g = __builtin_amdgcn_readfirstlane(g0);   // wave-uniform group idx
        const int2* p = ep + (g << 3);
        int2 r[8];
#pragma unroll
        for (int j = 0; j < 8; j++) r[j] = p[j];
        unsigned h[8];
#pragma unroll
        for (int j = 0; j < 8; j++)
            h[j] = fbu[((unsigned)(r[j].x & 0xFFFF) << 6) + lane];
#pragma unroll
        for (int j = 0; j < 8; j++) {
            float v = __int_as_float(r[j].y);
            int d = (r[j].x >> 16) & (BKT_NODES - 1);
            float* a = acc + d * D_FEAT + lane;
            atomicAdd(a,      v * __uint_as_float(h[j] << 16));          // feat lane
            atomicAdd(a + 64, v * __uint_as_float(h[j] & 0xffff0000u));  // feat lane+64
        }
    }
    // remainder (<8 edges): one edge per wave, parallel latency
    int e = (nfull << 3) + wid;
    if (e < cnt) {
        int2 r = ep[e];
        unsigned hv = fbu[((unsigned)(r.x & 0xFFFF) << 6) + lane];
        float v = __int_as_float(r.y);
        int d = (r.x >> 16) & (BKT_NODES - 1);
        float* a = acc + d * D_FEAT + lane;
        atomicAdd(a,      v * __uint_as_float(hv << 16));
        atomicAdd(a + 64, v * __uint_as_float(hv & 0xffff0000u));
    }
    __syncthreads();

    int f4 = tid & 31;
    float4 bv = bias4[f4];
    for (int n = tid >> 5; n < BKT_NODES; n += 32) {
        int node = (b << BKT_SHIFT) + n;
        if (node < N) {
            float4 a = acc4[n * 32 + f4];
            out4[(size_t)node * 32 + f4] =
                make_float4(a.x + bv.x, a.y + bv.y, a.z + bv.z, a.w + bv.w);
        }
    }
}

// ---------- fallback atomic path ----------

__global__ void init_bias_kernel(float4* __restrict__ out,
                                 const float4* __restrict__ bias, int n4) {
    int i = blockIdx.x * blockDim.x + threadIdx.x;
    if (i < n4) out[i] = bias[i & (D4 - 1)];
}

__global__ void spmm_edge_kernel(const int* __restrict__ src,
                                 const int* __restrict__ dst,
                                 const float* __restrict__ vals,
                                 const float4* __restrict__ feat,
                                 float* __restrict__ out, int n_edges) {
    int tid = blockIdx.x * blockDim.x + threadIdx.x;
    int e = tid >> 5;
    int lane = tid & 31;
    if (e >= n_edges) return;
    int s = src[e];
    int d = dst[e];
    float v = vals[e];
    float4 f = feat[(size_t)s * D4 + lane];
    float* o = out + (size_t)d * D_FEAT + lane * 4;
    atomicAdd(o + 0, v * f.x);
    atomicAdd(o + 1, v * f.y);
    atomicAdd(o + 2, v * f.z);
    atomicAdd(o + 3, v * f.w);
}

extern "C" void kernel_launch(void* const* d_in, const int* in_sizes, int n_in,
                              void* d_out, int out_size, void* d_ws, size_t ws_size,
                              hipStream_t stream) {
    const int* edge_index = (const int*)d_in[0];    // (2, E) int32
    const float* edge_vals = (const float*)d_in[1]; // (E,)
    const float* features  = (const float*)d_in[2]; // (N, 128)
    const float* bias      = (const float*)d_in[3]; // (128,)

    int E = in_sizes[1];
    int N = in_sizes[2] / D_FEAT;
    const int* src = edge_index;
    const int* dst = edge_index + E;
    float* out = (float*)d_out;

    int nbkt = (N + BKT_NODES - 1) >> BKT_SHIFT;

    // ws: fb16 (paired bf16) | spackA | counts | gcur | gbase
    size_t fb_bytes = (size_t)N * D_FEAT * 2;
    size_t sp_bytes = (size_t)E * 8;
    size_t needed = fb_bytes + sp_bytes + (size_t)MAXBKT * 4 * 3;

    bool ok = (ws_size >= needed) && (N >= 1) && (N <= 65536) && (E >= 1) &&
              (in_sizes[3] == D_FEAT) && (nbkt <= MAXBKT);

    if (ok) {
        char* wp = (char*)d_ws;
        unsigned* fb16 = (unsigned*)wp;  wp += fb_bytes;
        int2* spackA = (int2*)wp;        wp += sp_bytes;
        int* counts  = (int*)wp;         wp += (size_t)MAXBKT * 4;
        int* gcur    = (int*)wp;         wp += (size_t)MAXBKT * 4;
        int* gbase   = (int*)wp;

        hipMemsetAsync(counts, 0, (size_t)MAXBKT * 8, stream);  // counts + gcur

        k1_hist_cvt<<<K1_HIST_BLOCKS + K1_CVT_BLOCKS, 256, 0, stream>>>(
            dst, E, nbkt, counts, (const float4*)features, (uint4*)fb16, N);
        k3_partition<<<K3_BLOCKS, 512, 0, stream>>>(
            src, dst, edge_vals, E, nbkt, counts, gcur, gbase, spackA);
        k45_accum<<<nbkt, 1024, 0, stream>>>(
            counts, gbase, spackA, fb16, (const float4*)bias, (float4*)out, N);
    } else {
        int no4 = out_size / 4;
        {
            int block = 256, grid = (no4 + block - 1) / block;
            init_bias_kernel<<<grid, block, 0, stream>>>((float4*)out,
                                                         (const float4*)bias, no4);
        }
        {
            int block = 256;
            long long total = (long long)E * 32;
            int grid = (int)((total + block - 1) / block);
            spmm_edge_kernel<<<grid, block, 0, stream>>>(src, dst, edge_vals,
                                                         (const float4*)features,
                                                         out, E);
        }
    }
}

// Round 2
// 152.490 us; speedup vs baseline: 5.2385x; 5.2385x over previous
//
#include <hip/hip_runtime.h>
#include <hip/hip_bf16.h>

#define D_FEAT 128
#define D4 (D_FEAT / 4)
#define BKT_SHIFT 7            // 128 nodes per bucket
#define BKT_NODES 128
#define NCHUNK 256             // edge chunks (counting-sort columns)
#define MAXBKT 512
#define CAP 3072               // LDS sorted-edge capacity per bucket

// ---- K1: per-chunk LDS histogram over buckets -> M[c*MAXBKT + bkt] (full
//      row incl. zeros, so no memset needed); blocks >= NCHUNK convert
//      fp32 features -> bf16 table.
__global__ __launch_bounds__(256) void k1_hist_cvt(
        const int* __restrict__ dst, int E, int nbkt,
        int* __restrict__ M,
        const float4* __restrict__ fin, __hip_bfloat162* __restrict__ fout,
        int n4) {
    int c = blockIdx.x;
    int tid = threadIdx.x;
    if (c < NCHUNK) {
        __shared__ int hist[MAXBKT];
        for (int i = tid; i < MAXBKT; i += 256) hist[i] = 0;
        __syncthreads();
        int chunk = (E + NCHUNK - 1) / NCHUNK;
        int lo = c * chunk;
        int hi = min(lo + chunk, E);
        for (int i = lo + tid; i < hi; i += 256)
            atomicAdd(&hist[dst[i] >> BKT_SHIFT], 1);
        __syncthreads();
        for (int i = tid; i < MAXBKT; i += 256)
            M[c * MAXBKT + i] = hist[i];
    } else {
        int nb = gridDim.x - NCHUNK;
        int idx = (c - NCHUNK) * 256 + tid;
        int stride = nb * 256;
        for (int i = idx; i < n4; i += stride) {
            float4 f = fin[i];
            fout[2 * i + 0] = __float22bfloat162_rn(make_float2(f.x, f.y));
            fout[2 * i + 1] = __float22bfloat162_rn(make_float2(f.z, f.w));
        }
    }
}

// ---- K3: partition. Each block redundantly column-sums M to get bucket
//      totals (scan -> bases) and its own chunk's prefix within each bucket.
//      Identical partition layout to the old k2a/k2b path, zero extra
//      kernels, no global atomics. Block 0 publishes gbase[0..nbkt].
__global__ __launch_bounds__(512) void k3_partition(
        const int* __restrict__ src, const int* __restrict__ dst,
        const float* __restrict__ vals, int E, int nbkt,
        const int* __restrict__ M, int* __restrict__ gbase,
        int2* __restrict__ spackA) {
    __shared__ int s[MAXBKT];
    __shared__ int lcur[MAXBKT];
    int c = blockIdx.x;
    int tid = threadIdx.x;
    // column-sum + own-chunk prefix (coalesced across tid)
    int tot = 0, pre = 0;
    for (int cc = 0; cc < NCHUNK; ++cc) {
        int m = M[cc * MAXBKT + tid];
        tot += m;
        pre += (cc < c) ? m : 0;
    }
    s[tid] = tot;
    __syncthreads();
    // Hillis-Steele inclusive scan over MAXBKT with 512 threads
    for (int off = 1; off < MAXBKT; off <<= 1) {
        int t = (tid >= off) ? s[tid - off] : 0;
        __syncthreads();
        s[tid] += t;
        __syncthreads();
    }
    int incl = s[tid];
    int base = incl - tot;          // exclusive bucket base
    lcur[tid] = base + pre;
    if (c == 0) {
        if (tid < nbkt) gbase[tid] = base;
        if (tid == MAXBKT - 1) gbase[nbkt] = incl;   // rows >= nbkt are zero
    }
    __syncthreads();
    int chunk = (E + NCHUNK - 1) / NCHUNK;
    int lo = c * chunk;
    int hi = min(lo + chunk, E);
    for (int i = lo + tid; i < hi; i += 512) {
        int d = dst[i];
        int pos = atomicAdd(&lcur[d >> BKT_SHIFT], 1);
        spackA[pos] = make_int2((src[i] & 0xFFFF) | ((d & (BKT_NODES - 1)) << 16),
                                __float_as_int(vals[i]));
    }
}

// ---- K45: per-bucket counting sort INTO LDS + gather from LDS with
//      register accumulation (proven round-0 structure).
//      Overflow (cnt > CAP) falls back to global spackB for that bucket.
__global__ __launch_bounds__(1024) void k45_sort_gather(
        const int* __restrict__ gbase,
        const int2* __restrict__ spackA, int2* __restrict__ spackB,
        const __hip_bfloat162* __restrict__ feat,
        const float2* __restrict__ bias2, float2* __restrict__ out2,
        int N, int nbkt) {
    __shared__ int hist[BKT_NODES];
    __shared__ int sbuf[BKT_NODES];   // inclusive scan (kept for gather)
    __shared__ int lcur[BKT_NODES];
    __shared__ int2 ls[CAP];
    int b = blockIdx.x;
    int tid = threadIdx.x;
    int base = gbase[b];
    int end  = gbase[b + 1];
    int cnt = end - base;
    bool inlds = (cnt <= CAP);

    if (tid < BKT_NODES) hist[tid] = 0;
    __syncthreads();
    for (int i = tid; i < cnt; i += 1024)
        atomicAdd(&hist[(spackA[base + i].x >> 16) & (BKT_NODES - 1)], 1);
    __syncthreads();
    if (tid < BKT_NODES) sbuf[tid] = hist[tid];
    __syncthreads();
    for (int off = 1; off < BKT_NODES; off <<= 1) {
        int t = (tid < BKT_NODES && tid >= off) ? sbuf[tid - off] : 0;
        __syncthreads();
        if (tid < BKT_NODES) sbuf[tid] += t;
        __syncthreads();
    }
    if (tid < BKT_NODES) lcur[tid] = sbuf[tid] - hist[tid];
    __syncthreads();
    for (int i = tid; i < cnt; i += 1024) {
        int2 r = spackA[base + i];
        int p = atomicAdd(&lcur[(r.x >> 16) & (BKT_NODES - 1)], 1);
        if (inlds) ls[p] = r;
        else       spackB[base + p] = r;
    }
    __syncthreads();

    int wave = tid >> 6, lane = tid & 63;
    float2 bv = bias2[lane];
    for (int n = wave; n < BKT_NODES; n += 16) {
        int node = (b << BKT_SHIFT) + n;
        if (node >= N) break;
        int lbeg = sbuf[n] - hist[n];
        int lend = sbuf[n];
        float2 acc0 = bv;
        float2 acc1 = make_float2(0.f, 0.f);
        int e = lbeg;
        if (inlds) {
            for (; e + 8 <= lend; e += 8) {
                int2 p[8];
                __hip_bfloat162 h[8];
#pragma unroll
                for (int j = 0; j < 8; j++) p[j] = ls[e + j];
#pragma unroll
                for (int j = 0; j < 8; j++)
                    h[j] = feat[(size_t)(p[j].x & 0xFFFF) * 64 + lane];
#pragma unroll
                for (int j = 0; j < 8; j++) {
                    float v = __int_as_float(p[j].y);
                    float2 f = __bfloat1622float2(h[j]);
                    if (j & 1) { acc1.x += v * f.x; acc1.y += v * f.y; }
                    else       { acc0.x += v * f.x; acc0.y += v * f.y; }
                }
            }
            for (; e < lend; e++) {
                int2 p = ls[e];
                float v = __int_as_float(p.y);
                float2 f = __bfloat1622float2(feat[(size_t)(p.x & 0xFFFF) * 64 + lane]);
                acc0.x += v * f.x; acc0.y += v * f.y;
            }
        } else {
            for (; e + 8 <= lend; e += 8) {
                int2 p[8];
                __hip_bfloat162 h[8];
#pragma unroll
                for (int j = 0; j < 8; j++) p[j] = spackB[base + e + j];
#pragma unroll
                for (int j = 0; j < 8; j++)
                    h[j] = feat[(size_t)(p[j].x & 0xFFFF) * 64 + lane];
#pragma unroll
                for (int j = 0; j < 8; j++) {
                    float v = __int_as_float(p[j].y);
                    float2 f = __bfloat1622float2(h[j]);
                    if (j & 1) { acc1.x += v * f.x; acc1.y += v * f.y; }
                    else       { acc0.x += v * f.x; acc0.y += v * f.y; }
                }
            }
            for (; e < lend; e++) {
                int2 p = spackB[base + e];
                float v = __int_as_float(p.y);
                float2 f = __bfloat1622float2(feat[(size_t)(p.x & 0xFFFF) * 64 + lane]);
                acc0.x += v * f.x; acc0.y += v * f.y;
            }
        }
        acc0.x += acc1.x; acc0.y += acc1.y;
        out2[(size_t)node * 64 + lane] = acc0;
    }
}

// ---------- fallback atomic path ----------

__global__ void init_bias_kernel(float4* __restrict__ out,
                                 const float4* __restrict__ bias, int n4) {
    int i = blockIdx.x * blockDim.x + threadIdx.x;
    if (i < n4) out[i] = bias[i & (D4 - 1)];
}

__global__ void spmm_edge_kernel(const int* __restrict__ src,
                                 const int* __restrict__ dst,
                                 const float* __restrict__ vals,
                                 const float4* __restrict__ feat,
                                 float* __restrict__ out, int n_edges) {
    int tid = blockIdx.x * blockDim.x + threadIdx.x;
    int e = tid >> 5;
    int lane = tid & 31;
    if (e >= n_edges) return;
    int s = src[e];
    int d = dst[e];
    float v = vals[e];
    float4 f = feat[(size_t)s * D4 + lane];
    float* o = out + (size_t)d * D_FEAT + lane * 4;
    atomicAdd(o + 0, v * f.x);
    atomicAdd(o + 1, v * f.y);
    atomicAdd(o + 2, v * f.z);
    atomicAdd(o + 3, v * f.w);
}

extern "C" void kernel_launch(void* const* d_in, const int* in_sizes, int n_in,
                              void* d_out, int out_size, void* d_ws, size_t ws_size,
                              hipStream_t stream) {
    const int* edge_index = (const int*)d_in[0];    // (2, E) int32
    const float* edge_vals = (const float*)d_in[1]; // (E,)
    const float* features  = (const float*)d_in[2]; // (N, 128)
    const float* bias      = (const float*)d_in[3]; // (128,)

    int E = in_sizes[1];
    int N = in_sizes[2] / D_FEAT;
    const int* src = edge_index;
    const int* dst = edge_index + E;
    float* out = (float*)d_out;

    int nbkt = (N + BKT_NODES - 1) >> BKT_SHIFT;
    int n4 = N * D_FEAT / 4;

    // ws: fb16 | spackA | spackB | M[NCHUNK*MAXBKT] | gbase[MAXBKT+1]
    size_t fb_bytes = (size_t)N * D_FEAT * 2;
    size_t sp_bytes = (size_t)E * 8;
    size_t m_bytes  = (size_t)NCHUNK * MAXBKT * 4;
    size_t needed = fb_bytes + 2 * sp_bytes + m_bytes + (MAXBKT + 1) * 4;

    bool ok = (ws_size >= needed) && (N >= 1) && (N <= 65536) && (E >= 1) &&
              (in_sizes[3] == D_FEAT) && (nbkt <= MAXBKT);

    if (ok) {
        char* wp = (char*)d_ws;
        __hip_bfloat162* fb16 = (__hip_bfloat162*)wp;  wp += fb_bytes;
        int2* spackA = (int2*)wp;                      wp += sp_bytes;
        int2* spackB = (int2*)wp;                      wp += sp_bytes;
        int* M       = (int*)wp;                       wp += m_bytes;
        int* gbase   = (int*)wp;

        k1_hist_cvt<<<NCHUNK + 256, 256, 0, stream>>>(dst, E, nbkt, M,
                                                      (const float4*)features,
                                                      fb16, n4);
        k3_partition<<<NCHUNK, 512, 0, stream>>>(src, dst, edge_vals, E,
                                                 nbkt, M, gbase, spackA);
        k45_sort_gather<<<nbkt, 1024, 0, stream>>>(gbase, spackA, spackB,
                                                   fb16, (const float2*)bias,
                                                   (float2*)out, N, nbkt);
    } else {
        int no4 = out_size / 4;
        {
            int block = 256, grid = (no4 + block - 1) / block;
            init_bias_kernel<<<grid, block, 0, stream>>>((float4*)out,
                                                         (const float4*)bias, no4);
        }
        {
            int block = 256;
            long long total = (long long)E * 32;
            int grid = (int)((total + block - 1) / block);
            spmm_edge_kernel<<<grid, block, 0, stream>>>(src, dst, edge_vals,
                                                         (const float4*)features,
                                                         out, E);
        }
    }
}